// Round 2
// baseline (240.422 us; speedup 1.0000x reference)
//
#include <hip/hip_runtime.h>
#include <hip/hip_bf16.h>

typedef short v8s __attribute__((ext_vector_type(8)));
typedef short v4s __attribute__((ext_vector_type(4)));
typedef float v4f __attribute__((ext_vector_type(4)));

#define LDK 72                    // padded LDS row stride (bf16 elems): 144 B, 16B-aligned rows
#define SCALE_LOG2E 0.18033688f   // (1/sqrt(64)) * log2(e), folded into Q at staging
#define RESCALE_THR 8.0f          // defer-max threshold (T13): P bounded by 2^8, bf16-safe

struct MMRAParams {
    const float* q[4];
    const float* k[4];
    const float* v[4];
    const int*   rg[4];
    const int*   mask;
    float*       out;
};

// Native packed fp32->bf16 (RNE), 1 VALU op for a pair.
__device__ __forceinline__ unsigned pkbf(float a, float b) {
    unsigned r;
    asm("v_cvt_pk_bf16_f32 %0, %1, %2" : "=v"(r) : "v"(a), "v"(b));
    return r;   // low = bf16(a), high = bf16(b)
}

// 16x16x16 bf16 MFMA: A-frag lane holds k = quad*4+r (4 bf16) — matches S^T's
// native per-lane layout, so P never round-trips LDS.
__device__ __forceinline__ v4f mfma16(v4s a, v4s b, v4f c) {
#if __has_builtin(__builtin_amdgcn_mfma_f32_16x16x16bf16_1k)
    return __builtin_amdgcn_mfma_f32_16x16x16bf16_1k(a, b, c, 0, 0, 0);
#elif __has_builtin(__builtin_amdgcn_mfma_f32_16x16x16_bf16)
    return __builtin_amdgcn_mfma_f32_16x16x16_bf16(a, b, c, 0, 0, 0);
#else
    asm("v_mfma_f32_16x16x16_bf16 %0, %1, %2, %0" : "+v"(c) : "v"(a), "v"(b));
    return c;
#endif
}

__global__ __launch_bounds__(512, 4)
void mmra_attn(MMRAParams P) {
    const int bid = blockIdx.x;       // 512 blocks; bid&7 = b*4+h for XCD L2 locality
    const int h = bid & 3;
    const int b = (bid >> 2) & 1;
    const int n = bid >> 3;           // region 0..63
    const int H0 = ((n >> 4) & 3) << 2;
    const int W0 = ((n >> 2) & 3) << 2;
    const int D0 = (n & 3) << 2;

    const int tid  = threadIdx.x;
    const int wave = tid >> 6;        // 8 waves: wave = qmod*2 + mt-half
    const int qm   = wave >> 1;       // q-modality of this wave
    const int mth  = wave & 1;        // which half of the 4 mt tiles (mt = mth*2 + m2)
    const int lane = tid & 63;
    const int l15  = lane & 15;
    const int quad = lane >> 4;

    // LDS union: Q-staging scratch (8 waves x 32 rows x LDK = 36864 B) overlaps
    // the K/V tiles (2 x 4608 elems = 18432 B) used during the chunk loop.
    __shared__ __align__(16) ushort SMEM[18432];
    ushort* Klds = SMEM;            // [token][c]  (bf16)  4608 elems
    ushort* Vlds = SMEM + 4608;     // [c][token]  (bf16, transposed) 4608 elems

    const int bh_base = (b * 256 + h * 64) * 4096;        // fp32 elem idx base
    const int rgbase  = ((b * 4 + h) * 64 + n) * 4;

    const bool actm[4] = { P.mask[b * 4 + 0] != 0, P.mask[b * 4 + 1] != 0,
                           P.mask[b * 4 + 2] != 0, P.mask[b * 4 + 3] != 0 };

    auto kptr = [&](int m) { return (m == 0) ? P.k[0] : (m == 1) ? P.k[1] : (m == 2) ? P.k[2] : P.k[3]; };
    auto vptr = [&](int m) { return (m == 0) ? P.v[0] : (m == 1) ? P.v[1] : (m == 2) ? P.v[2] : P.v[3]; };
    auto rptr = [&](int m) { return (m == 0) ? P.rg[0] : (m == 1) ? P.rg[1] : (m == 2) ? P.rg[2] : P.rg[3]; };

    // ---------------- chunk prefetch registers (2 token-groups per wave) ----------------
    float4 pkf[2], pvf[2];
    auto prefetch = [&](int cj) {
        const int mod = cj >> 2, j = cj & 3;
        const int g = rptr(mod)[rgbase + j] & 63;
        const int goff = (((g >> 4) & 3) << 10) + (((g >> 2) & 3) << 6) + ((g & 3) << 2);
        const float* ks = kptr(mod);
        const float* vs = vptr(mod);
        const int off0 = bh_base + lane * 4096 + goff;
        #pragma unroll
        for (int i = 0; i < 2; ++i) {
            const int pq = wave * 2 + i;
            const int off = off0 + (pq >> 2) * 256 + (pq & 3) * 16;
            pkf[i] = *(const float4*)(ks + off);
            pvf[i] = *(const float4*)(vs + off);
        }
    };

    prefetch(0);   // chunk-0 loads overlap Q staging below

    // ------- Q staging: per-wave PRIVATE 32 rows of SMEM scratch, ONE drain -------
    // Q pre-scaled by SCALE_LOG2E so S comes out directly in log2 domain.
    v8s qfrag[2][2];
    {
        ushort* qbuf = SMEM + wave * 2304;     // 32 rows x LDK, private
        const float* qsrc = (qm == 0) ? P.q[0] : (qm == 1) ? P.q[1] : (qm == 2) ? P.q[2] : P.q[3];
        #pragma unroll
        for (int rb2 = 0; rb2 < 2; ++rb2) {       // local mt within this wave's half
            const int rb = mth * 2 + rb2;         // global mt = p (y) coordinate
            #pragma unroll
            for (int i = 0; i < 4; ++i) {         // i = x coordinate; c = lane
                int off = bh_base + lane * 4096 + (H0 + rb) * 256 + (W0 + i) * 16 + D0;
                float4 cv = *(const float4*)(qsrc + off);
                unsigned q01 = pkbf(cv.x * SCALE_LOG2E, cv.y * SCALE_LOG2E);
                unsigned q23 = pkbf(cv.z * SCALE_LOG2E, cv.w * SCALE_LOG2E);
                ushort* qb = &qbuf[(rb2 * 16 + i * 4) * LDK + lane];
                qb[0 * LDK] = (ushort)q01;
                qb[1 * LDK] = (ushort)(q01 >> 16);
                qb[2 * LDK] = (ushort)q23;
                qb[3 * LDK] = (ushort)(q23 >> 16);
            }
        }
        __asm__ volatile("s_waitcnt lgkmcnt(0)" ::: "memory");   // wave-local write->read
        #pragma unroll
        for (int m2 = 0; m2 < 2; ++m2) {
            qfrag[m2][0] = *(const v8s*)&qbuf[(m2 * 16 + l15) * LDK + quad * 8];
            qfrag[m2][1] = *(const v8s*)&qbuf[(m2 * 16 + l15) * LDK + 32 + quad * 8];
        }
    }
    // loop's first __syncthreads() (before K/V staging overwrites SMEM) protects the
    // scratch reads above across waves.

    v4f  oacc[2][4];              // [m2][t]: D[row=quad*4+r = q][col=l15 = d-within-t]
    float mrow[2], lrow[2];       // softmax state per m2, indexed by q = l15 (dup across quads)
    #pragma unroll
    for (int m2 = 0; m2 < 2; ++m2) {
        mrow[m2] = -1e30f; lrow[m2] = 0.f;
        #pragma unroll
        for (int t = 0; t < 4; ++t) oacc[m2][t] = (v4f){0.f, 0.f, 0.f, 0.f};
    }

    #pragma unroll 1
    for (int cj = 0; cj < 16; ++cj) {             // chunk = (modality, topk-slot)
        const bool act = actm[cj >> 2];           // block-uniform
        if (act) {
            __syncthreads();   // prior chunk's K/V frag reads (and Q scratch) complete
            #pragma unroll
            for (int i = 0; i < 2; ++i) {
                const int pq = wave * 2 + i;
                unsigned k01 = pkbf(pkf[i].x, pkf[i].y);
                unsigned k23 = pkbf(pkf[i].z, pkf[i].w);
                ushort* kb = &Klds[(pq * 4) * LDK + lane];
                kb[0 * LDK] = (ushort)k01;
                kb[1 * LDK] = (ushort)(k01 >> 16);
                kb[2 * LDK] = (ushort)k23;
                kb[3 * LDK] = (ushort)(k23 >> 16);
                uint2 vv;
                vv.x = pkbf(pvf[i].x, pvf[i].y);
                vv.y = pkbf(pvf[i].z, pvf[i].w);
                *(uint2*)&Vlds[lane * LDK + pq * 4] = vv;   // transposed, packed 8B
            }
        }
        if (cj < 15) prefetch(cj + 1);     // overlaps phases A+B below
        if (!act) continue;                // uniform skip == -inf mask
        __syncthreads();

        // ===== PHASE A: QK^T + softmax; P stays IN REGISTERS (pa), no LDS round-trip =====
        uint2 pa[2][4];    // [m2][nt]: bf16x4 A-frag for PV: P[q=l15][key=nt*16+quad*4+r]
        {
            float sv[2][4][4];
            #pragma unroll
            for (int nt = 0; nt < 4; ++nt) {
                v8s kf0 = *(const v8s*)&Klds[(nt * 16 + l15) * LDK + quad * 8];
                v8s kf1 = *(const v8s*)&Klds[(nt * 16 + l15) * LDK + 32 + quad * 8];
                #pragma unroll
                for (int m2 = 0; m2 < 2; ++m2) {
                    v4f acc = (v4f){0.f, 0.f, 0.f, 0.f};
                    acc = __builtin_amdgcn_mfma_f32_16x16x32_bf16(kf0, qfrag[m2][0], acc, 0, 0, 0);
                    acc = __builtin_amdgcn_mfma_f32_16x16x32_bf16(kf1, qfrag[m2][1], acc, 0, 0, 0);
                    #pragma unroll
                    for (int r = 0; r < 4; ++r) sv[m2][nt][r] = acc[r];
                }
            }
            #pragma unroll
            for (int m2 = 0; m2 < 2; ++m2) {
                // column (=q) max: v_max3-friendly tree, then across quads (xor 16, 32)
                float mx;
                {
                    float a0 = fmaxf(fmaxf(sv[m2][0][0], sv[m2][0][1]), sv[m2][0][2]);
                    float a1 = fmaxf(fmaxf(sv[m2][0][3], sv[m2][1][0]), sv[m2][1][1]);
                    float a2 = fmaxf(fmaxf(sv[m2][1][2], sv[m2][1][3]), sv[m2][2][0]);
                    float a3 = fmaxf(fmaxf(sv[m2][2][1], sv[m2][2][2]), sv[m2][2][3]);
                    float a4 = fmaxf(fmaxf(sv[m2][3][0], sv[m2][3][1]), sv[m2][3][2]);
                    mx = fmaxf(fmaxf(fmaxf(a0, a1), a2), fmaxf(fmaxf(a3, a4), sv[m2][3][3]));
                }
                mx = fmaxf(mx, __shfl_xor(mx, 16));
                mx = fmaxf(mx, __shfl_xor(mx, 32));

                // T13 defer-max: only rescale when some row's max grew by > THR.
                if (!__all(mx - mrow[m2] <= RESCALE_THR)) {
                    const float mnew  = fmaxf(mrow[m2], mx);
                    const float alpha = exp2f(mrow[m2] - mnew);
                    mrow[m2] = mnew;
                    lrow[m2] *= alpha;
                    float alpha_row[4];
                    #pragma unroll
                    for (int r = 0; r < 4; ++r)
                        alpha_row[r] = __shfl(alpha, (quad << 4) | (quad * 4 + r));
                    #pragma unroll
                    for (int t = 0; t < 4; ++t)
                        #pragma unroll
                        for (int r = 0; r < 4; ++r) oacc[m2][t][r] *= alpha_row[r];
                }
                const float mcur = mrow[m2];

                // P = exp2(S - m), packed straight into MFMA A-frags (registers only)
                float rsum = 0.f;
                #pragma unroll
                for (int nt = 0; nt < 4; ++nt) {
                    float p0 = exp2f(sv[m2][nt][0] - mcur);
                    float p1 = exp2f(sv[m2][nt][1] - mcur);
                    float p2 = exp2f(sv[m2][nt][2] - mcur);
                    float p3 = exp2f(sv[m2][nt][3] - mcur);
                    rsum += (p0 + p1) + (p2 + p3);
                    pa[m2][nt].x = pkbf(p0, p1);
                    pa[m2][nt].y = pkbf(p2, p3);
                }
                rsum += __shfl_xor(rsum, 16);
                rsum += __shfl_xor(rsum, 32);
                lrow[m2] += rsum;
            }
        }

        // ===== PHASE B: PV via 16x16x16 MFMA, V as b64 B-frags; no drains, no barriers =====
        #pragma unroll
        for (int t = 0; t < 4; ++t) {
            #pragma unroll
            for (int nt = 0; nt < 4; ++nt) {
                v4s vf = *(const v4s*)&Vlds[(t * 16 + l15) * LDK + nt * 16 + quad * 4];
                oacc[0][t] = mfma16(__builtin_bit_cast(v4s, pa[0][nt]), vf, oacc[0][t]);
                oacc[1][t] = mfma16(__builtin_bit_cast(v4s, pa[1][nt]), vf, oacc[1][t]);
            }
        }
    }

    // ---------------- epilogue: O /= l (quad-transposed), seq2grid, float4 stores ----------------
    const int obase = (qm * 2 + b) * 1048576 + h * 64 * 4096;
    #pragma unroll
    for (int m2 = 0; m2 < 2; ++m2) {
        const int mt = mth * 2 + m2;
        const float invq = 1.0f / lrow[m2];
        float inv_row[4];
        #pragma unroll
        for (int r = 0; r < 4; ++r)
            inv_row[r] = __shfl(invq, (quad << 4) | (quad * 4 + r));
        #pragma unroll
        for (int t = 0; t < 4; ++t) {
            float4 ov;
            ov.x = oacc[m2][t][0] * inv_row[0];
            ov.y = oacc[m2][t][1] * inv_row[1];
            ov.z = oacc[m2][t][2] * inv_row[2];
            ov.w = oacc[m2][t][3] * inv_row[3];
            int off = obase + (t * 16 + l15) * 4096 + (H0 + mt) * 256 + (W0 + quad) * 16 + D0;
            *(float4*)(P.out + off) = ov;
        }
    }
}

extern "C" void kernel_launch(void* const* d_in, const int* in_sizes, int n_in,
                              void* d_out, int out_size, void* d_ws, size_t ws_size,
                              hipStream_t stream) {
    (void)in_sizes; (void)n_in; (void)out_size; (void)d_ws; (void)ws_size;
    MMRAParams P;
    P.mask = (const int*)d_in[0];
    for (int i = 0; i < 4; ++i) {
        P.q[i]  = (const float*)d_in[1 + i];
        P.k[i]  = (const float*)d_in[5 + i];
        P.v[i]  = (const float*)d_in[9 + i];
        P.rg[i] = (const int*)d_in[13 + i];
    }
    P.out = (float*)d_out;
    hipLaunchKernelGGL(mmra_attn, dim3(512), dim3(512), 0, stream, P);
}

// Round 3
// 240.383 us; speedup vs baseline: 1.0002x; 1.0002x over previous
//
#include <hip/hip_runtime.h>
#include <hip/hip_bf16.h>

typedef short v8s __attribute__((ext_vector_type(8)));
typedef short v4s __attribute__((ext_vector_type(4)));
typedef float v4f __attribute__((ext_vector_type(4)));

#define LDK 72                    // padded LDS row stride (bf16 elems): 144 B
#define SCALE_LOG2E 0.18033688f   // (1/sqrt(64)) * log2(e), folded into Q at staging
#define RESCALE_THR 8.0f          // defer-max threshold (T13)

struct MMRAParams {
    const float* q[4];
    const float* k[4];
    const float* v[4];
    const int*   rg[4];
    const int*   mask;
    float*       out;
};

// Native packed fp32->bf16 (RNE), 1 VALU op per pair.
__device__ __forceinline__ unsigned pkbf(float a, float b) {
    unsigned r;
    asm("v_cvt_pk_bf16_f32 %0, %1, %2" : "=v"(r) : "v"(a), "v"(b));
    return r;   // low = bf16(a), high = bf16(b)
}

// 16x16x16 bf16 MFMA: A-frag k = quad*4+r matches S^T's native register layout.
__device__ __forceinline__ v4f mfma16(v4s a, v4s b, v4f c) {
#if __has_builtin(__builtin_amdgcn_mfma_f32_16x16x16bf16_1k)
    return __builtin_amdgcn_mfma_f32_16x16x16bf16_1k(a, b, c, 0, 0, 0);
#elif __has_builtin(__builtin_amdgcn_mfma_f32_16x16x16_bf16)
    return __builtin_amdgcn_mfma_f32_16x16x16_bf16(a, b, c, 0, 0, 0);
#else
    asm("v_mfma_f32_16x16x16_bf16 %0, %1, %2, %0" : "+v"(c) : "v"(a), "v"(b));
    return c;
#endif
}

__global__ __launch_bounds__(256, 2)
void mmra_attn(MMRAParams P) {
    const int bid = blockIdx.x;       // 512 blocks; bid&7 = b*4+h for XCD L2 locality
    const int h = bid & 3;
    const int b = (bid >> 2) & 1;
    const int n = bid >> 3;           // region 0..63
    const int H0 = ((n >> 4) & 3) << 2;
    const int W0 = ((n >> 2) & 3) << 2;
    const int D0 = (n & 3) << 2;

    const int tid  = threadIdx.x;
    const int wave = tid >> 6;        // 4 waves: wave = q-modality; each wave does all 4 mt
    const int lane = tid & 63;
    const int l15  = lane & 15;
    const int quad = lane >> 4;

    // Double-buffered K/V: buf = [K 64x72][V 64x72] = 9216 ushort; 2 bufs = 36864 B.
    // Q-staging scratch (4 waves x 64 rows x 72 = whole SMEM) overlaps, protected by
    // the prologue barriers.
    __shared__ __align__(16) ushort SMEM[18432];

    const int bh_base = (b * 256 + h * 64) * 4096;        // fp32 elem idx base
    const int rgbase  = ((b * 4 + h) * 64 + n) * 4;

    const bool actm[4] = { P.mask[b * 4 + 0] != 0, P.mask[b * 4 + 1] != 0,
                           P.mask[b * 4 + 2] != 0, P.mask[b * 4 + 3] != 0 };

    auto kptr = [&](int m) { return (m == 0) ? P.k[0] : (m == 1) ? P.k[1] : (m == 2) ? P.k[2] : P.k[3]; };
    auto vptr = [&](int m) { return (m == 0) ? P.v[0] : (m == 1) ? P.v[1] : (m == 2) ? P.v[2] : P.v[3]; };
    auto rptr = [&](int m) { return (m == 0) ? P.rg[0] : (m == 1) ? P.rg[1] : (m == 2) ? P.rg[2] : P.rg[3]; };

    // ---- active-chunk list packed as nibbles (block-uniform, stays scalar) ----
    unsigned long long clist = 0ull; int nc = 0;
    for (int m = 0; m < 4; ++m) {
        if (actm[m]) {
            #pragma unroll
            for (int s = 0; s < 4; ++s) { clist |= ((unsigned long long)(m * 4 + s)) << (4 * nc); ++nc; }
        }
    }

    // ---------------- chunk prefetch registers (4 token-groups per wave) ----------------
    float4 pkf[4], pvf[4];
    auto prefetch = [&](int cj) {
        const int mod = cj >> 2, j = cj & 3;
        const int g = rptr(mod)[rgbase + j] & 63;
        const int goff = (((g >> 4) & 3) << 10) + (((g >> 2) & 3) << 6) + ((g & 3) << 2);
        const float* ks = kptr(mod);
        const float* vs = vptr(mod);
        const int off0 = bh_base + lane * 4096 + goff;
        #pragma unroll
        for (int i = 0; i < 4; ++i) {
            const int pq = wave * 4 + i;
            const int off = off0 + (pq >> 2) * 256 + (pq & 3) * 16;
            pkf[i] = *(const float4*)(ks + off);
            pvf[i] = *(const float4*)(vs + off);
        }
    };

    auto stage = [&](int buf) {
        ushort* Kb = SMEM + buf * 9216;
        ushort* Vb = Kb + 4608;
        #pragma unroll
        for (int i = 0; i < 4; ++i) {
            const int pq = wave * 4 + i;
            unsigned k01 = pkbf(pkf[i].x, pkf[i].y);
            unsigned k23 = pkbf(pkf[i].z, pkf[i].w);
            ushort* kb = &Kb[(pq * 4) * LDK + lane];
            kb[0 * LDK] = (ushort)k01;
            kb[1 * LDK] = (ushort)(k01 >> 16);
            kb[2 * LDK] = (ushort)k23;
            kb[3 * LDK] = (ushort)(k23 >> 16);
            uint2 vv;
            vv.x = pkbf(pvf[i].x, pvf[i].y);
            vv.y = pkbf(pvf[i].z, pvf[i].w);
            *(uint2*)&Vb[lane * LDK + pq * 4] = vv;   // transposed, packed 8B
        }
    };

    prefetch((int)(clist & 15));   // chunk-0 loads overlap Q staging below

    // ------- Q staging: per-wave PRIVATE 64 rows of SMEM scratch, ONE drain -------
    v8s qfrag[4][2];
    {
        ushort* qbuf = SMEM + wave * 4608;
        const float* qsrc = (wave == 0) ? P.q[0] : (wave == 1) ? P.q[1] : (wave == 2) ? P.q[2] : P.q[3];
        #pragma unroll
        for (int rb = 0; rb < 4; ++rb) {          // rb = mt (p coordinate)
            #pragma unroll
            for (int i = 0; i < 4; ++i) {         // i = x coordinate; c = lane
                int off = bh_base + lane * 4096 + (H0 + rb) * 256 + (W0 + i) * 16 + D0;
                float4 cv = *(const float4*)(qsrc + off);
                unsigned q01 = pkbf(cv.x * SCALE_LOG2E, cv.y * SCALE_LOG2E);
                unsigned q23 = pkbf(cv.z * SCALE_LOG2E, cv.w * SCALE_LOG2E);
                ushort* qb = &qbuf[(rb * 16 + i * 4) * LDK + lane];
                qb[0 * LDK] = (ushort)q01;
                qb[1 * LDK] = (ushort)(q01 >> 16);
                qb[2 * LDK] = (ushort)q23;
                qb[3 * LDK] = (ushort)(q23 >> 16);
            }
        }
        __asm__ volatile("s_waitcnt lgkmcnt(0)" ::: "memory");   // wave-local write->read
        #pragma unroll
        for (int rb = 0; rb < 4; ++rb) {
            qfrag[rb][0] = *(const v8s*)&qbuf[(rb * 16 + l15) * LDK + quad * 8];
            qfrag[rb][1] = *(const v8s*)&qbuf[(rb * 16 + l15) * LDK + 32 + quad * 8];
        }
    }
    __syncthreads();               // scratch reads done before buf0 staging overwrites
    stage(0);
    if (nc > 1) prefetch((int)((clist >> 4) & 15));
    __syncthreads();               // buf0 visible to all waves

    v4f  oacc[4][4];              // [mt][t]: D[row=quad*4+r = q][col=l15 = d-within-t]
    float mrow[4], lrow[4];       // softmax state per mt, indexed by q = l15 (dup across quads)
    #pragma unroll
    for (int mt = 0; mt < 4; ++mt) {
        mrow[mt] = -1e30f; lrow[mt] = 0.f;
        #pragma unroll
        for (int t = 0; t < 4; ++t) oacc[mt][t] = (v4f){0.f, 0.f, 0.f, 0.f};
    }

    int cur = 0;
    #pragma unroll 1
    for (int i = 0; i < nc; ++i) {             // all listed chunks are active
        // ---- overlap: stage NEXT chunk into other buffer; issue prefetch i+2 ----
        if (i + 1 < nc) {
            stage(cur ^ 1);
            if (i + 2 < nc) prefetch((int)((clist >> (4 * (i + 2))) & 15));
        }
        const ushort* Kb = SMEM + cur * 9216;
        const ushort* Vb = Kb + 4608;

        // ===== PHASE A: QK^T + softmax; P stays in registers =====
        float sv[4][4][4];      // [mt][nt][r]: key = nt*16+quad*4+r, q = l15
        #pragma unroll
        for (int nt = 0; nt < 4; ++nt) {
            v8s kf0 = *(const v8s*)&Kb[(nt * 16 + l15) * LDK + quad * 8];
            v8s kf1 = *(const v8s*)&Kb[(nt * 16 + l15) * LDK + 32 + quad * 8];
            __builtin_amdgcn_s_setprio(1);
            #pragma unroll
            for (int mt = 0; mt < 4; ++mt) {
                v4f acc = (v4f){0.f, 0.f, 0.f, 0.f};
                acc = __builtin_amdgcn_mfma_f32_16x16x32_bf16(kf0, qfrag[mt][0], acc, 0, 0, 0);
                acc = __builtin_amdgcn_mfma_f32_16x16x32_bf16(kf1, qfrag[mt][1], acc, 0, 0, 0);
                #pragma unroll
                for (int r = 0; r < 4; ++r) sv[mt][nt][r] = acc[r];
            }
            __builtin_amdgcn_s_setprio(0);
        }
        uint2 pa[4][4];    // [mt][nt]: bf16x4 A-frag: P[q=l15][key=nt*16+quad*4+r]
        #pragma unroll
        for (int mt = 0; mt < 4; ++mt) {
            // column (=q) max: v_max3-friendly tree, then across quads (xor 16, 32)
            float mx;
            {
                float a0 = fmaxf(fmaxf(sv[mt][0][0], sv[mt][0][1]), sv[mt][0][2]);
                float a1 = fmaxf(fmaxf(sv[mt][0][3], sv[mt][1][0]), sv[mt][1][1]);
                float a2 = fmaxf(fmaxf(sv[mt][1][2], sv[mt][1][3]), sv[mt][2][0]);
                float a3 = fmaxf(fmaxf(sv[mt][2][1], sv[mt][2][2]), sv[mt][2][3]);
                float a4 = fmaxf(fmaxf(sv[mt][3][0], sv[mt][3][1]), sv[mt][3][2]);
                mx = fmaxf(fmaxf(fmaxf(a0, a1), a2), fmaxf(fmaxf(a3, a4), sv[mt][3][3]));
            }
            mx = fmaxf(mx, __shfl_xor(mx, 16));
            mx = fmaxf(mx, __shfl_xor(mx, 32));

            // T13 defer-max: only rescale when some row's max grew by > THR (wave-uniform)
            if (!__all(mx - mrow[mt] <= RESCALE_THR)) {
                const float mnew  = fmaxf(mrow[mt], mx);
                const float alpha = exp2f(mrow[mt] - mnew);
                mrow[mt] = mnew;
                lrow[mt] *= alpha;
                float alpha_row[4];
                #pragma unroll
                for (int r = 0; r < 4; ++r)
                    alpha_row[r] = __shfl(alpha, (quad << 4) | (quad * 4 + r));
                #pragma unroll
                for (int t = 0; t < 4; ++t)
                    #pragma unroll
                    for (int r = 0; r < 4; ++r) oacc[mt][t][r] *= alpha_row[r];
            }
            const float mcur = mrow[mt];

            float rsum = 0.f;
            #pragma unroll
            for (int nt = 0; nt < 4; ++nt) {
                float p0 = exp2f(sv[mt][nt][0] - mcur);
                float p1 = exp2f(sv[mt][nt][1] - mcur);
                float p2 = exp2f(sv[mt][nt][2] - mcur);
                float p3 = exp2f(sv[mt][nt][3] - mcur);
                rsum += (p0 + p1) + (p2 + p3);
                pa[mt][nt].x = pkbf(p0, p1);
                pa[mt][nt].y = pkbf(p2, p3);
            }
            rsum += __shfl_xor(rsum, 16);
            rsum += __shfl_xor(rsum, 32);
            lrow[mt] += rsum;
        }

        // ===== PHASE B: PV via 16x16x16 MFMA; vf shared across all 4 mt =====
        __builtin_amdgcn_s_setprio(1);
        #pragma unroll
        for (int t = 0; t < 4; ++t) {
            #pragma unroll
            for (int nt = 0; nt < 4; ++nt) {
                v4s vf = *(const v4s*)&Vb[(t * 16 + l15) * LDK + nt * 16 + quad * 4];
                #pragma unroll
                for (int mt = 0; mt < 4; ++mt)
                    oacc[mt][t] = mfma16(__builtin_bit_cast(v4s, pa[mt][nt]), vf, oacc[mt][t]);
            }
        }
        __builtin_amdgcn_s_setprio(0);

        __syncthreads();     // staged chunk i+1 visible; buf[cur] reads complete
        cur ^= 1;
    }

    // ---------------- epilogue: O /= l (quad-transposed), seq2grid, float4 stores ----------------
    const int obase = (wave * 2 + b) * 1048576 + h * 64 * 4096;
    #pragma unroll
    for (int mt = 0; mt < 4; ++mt) {
        const float invq = 1.0f / lrow[mt];
        float inv_row[4];
        #pragma unroll
        for (int r = 0; r < 4; ++r)
            inv_row[r] = __shfl(invq, (quad << 4) | (quad * 4 + r));
        #pragma unroll
        for (int t = 0; t < 4; ++t) {
            float4 ov;
            ov.x = oacc[mt][t][0] * inv_row[0];
            ov.y = oacc[mt][t][1] * inv_row[1];
            ov.z = oacc[mt][t][2] * inv_row[2];
            ov.w = oacc[mt][t][3] * inv_row[3];
            int off = obase + (t * 16 + l15) * 4096 + (H0 + mt) * 256 + (W0 + quad) * 16 + D0;
            *(float4*)(P.out + off) = ov;
        }
    }
}

extern "C" void kernel_launch(void* const* d_in, const int* in_sizes, int n_in,
                              void* d_out, int out_size, void* d_ws, size_t ws_size,
                              hipStream_t stream) {
    (void)in_sizes; (void)n_in; (void)out_size; (void)d_ws; (void)ws_size;
    MMRAParams P;
    P.mask = (const int*)d_in[0];
    for (int i = 0; i < 4; ++i) {
        P.q[i]  = (const float*)d_in[1 + i];
        P.k[i]  = (const float*)d_in[5 + i];
        P.v[i]  = (const float*)d_in[9 + i];
        P.rg[i] = (const int*)d_in[13 + i];
    }
    P.out = (float*)d_out;
    hipLaunchKernelGGL(mmra_attn, dim3(512), dim3(256), 0, stream, P);
}

// Round 7
// 223.989 us; speedup vs baseline: 1.0734x; 1.0732x over previous
//
#include <hip/hip_runtime.h>
#include <hip/hip_bf16.h>

typedef short v8s __attribute__((ext_vector_type(8)));
typedef short v4s __attribute__((ext_vector_type(4)));
typedef float v4f __attribute__((ext_vector_type(4)));

#define LDK 72                    // padded LDS row stride (bf16 elems): 144 B
#define SCALE_LOG2E 0.18033688f   // (1/sqrt(64)) * log2(e), folded into Q at staging
#define RESCALE_THR 8.0f          // defer-max threshold (T13)

struct MMRAParams {
    const float* q[4];
    const float* k[4];
    const float* v[4];
    const int*   rg[4];
    const int*   mask;
    float*       out;
};

// Native packed fp32->bf16 (RNE), 1 VALU op per pair. (Non-trans op; verified r1-r3.)
__device__ __forceinline__ unsigned pkbf(float a, float b) {
    unsigned r;
    asm("v_cvt_pk_bf16_f32 %0, %1, %2" : "=v"(r) : "v"(a), "v"(b));
    return r;   // low = bf16(a), high = bf16(b)
}

// Single-instruction 2^x. Compiler-known TRANS op (hazard wait inserted by backend).
// Args are max-subtracted (<= RESCALE_THR); denormal-output range unreachable except
// alpha-underflow-to-0 which is the mathematically correct result.
__device__ __forceinline__ float fexp2(float x) {
#if __has_builtin(__builtin_amdgcn_exp2f)
    return __builtin_amdgcn_exp2f(x);
#else
    return exp2f(x);
#endif
}

// 16x16x16 bf16 MFMA: A-frag k = quad*4+r matches S^T's native register layout.
// (Verified for PV in rounds 2-3.)
__device__ __forceinline__ v4f mfma16(v4s a, v4s b, v4f c) {
#if __has_builtin(__builtin_amdgcn_mfma_f32_16x16x16bf16_1k)
    return __builtin_amdgcn_mfma_f32_16x16x16bf16_1k(a, b, c, 0, 0, 0);
#elif __has_builtin(__builtin_amdgcn_mfma_f32_16x16x16_bf16)
    return __builtin_amdgcn_mfma_f32_16x16x16_bf16(a, b, c, 0, 0, 0);
#else
    asm("v_mfma_f32_16x16x16_bf16 %0, %1, %2, %0" : "+v"(c) : "v"(a), "v"(b));
    return c;
#endif
}

__global__ __launch_bounds__(256, 2)
void mmra_attn(MMRAParams P) {
    const int bid = blockIdx.x;       // 512 blocks; bid&7 = b*4+h for XCD L2 locality
    const int h = bid & 3;
    const int b = (bid >> 2) & 1;
    const int n = bid >> 3;           // region 0..63
    const int H0 = ((n >> 4) & 3) << 2;
    const int W0 = ((n >> 2) & 3) << 2;
    const int D0 = (n & 3) << 2;

    const int tid  = threadIdx.x;
    const int wave = tid >> 6;        // 4 waves: wave = q-modality; each wave does all 4 mt
    const int lane = tid & 63;
    const int l15  = lane & 15;
    const int quad = lane >> 4;

    // Double-buffered K/V: buf = [K 64x72][V 64x72] = 9216 ushort; 2 bufs = 36864 B.
    __shared__ __align__(16) ushort SMEM[18432];

    const int bh_base = (b * 256 + h * 64) * 4096;        // fp32 elem idx base
    const int rgbase  = ((b * 4 + h) * 64 + n) * 4;

    const bool actm[4] = { P.mask[b * 4 + 0] != 0, P.mask[b * 4 + 1] != 0,
                           P.mask[b * 4 + 2] != 0, P.mask[b * 4 + 3] != 0 };

    auto kptr = [&](int m) { return (m == 0) ? P.k[0] : (m == 1) ? P.k[1] : (m == 2) ? P.k[2] : P.k[3]; };
    auto vptr = [&](int m) { return (m == 0) ? P.v[0] : (m == 1) ? P.v[1] : (m == 2) ? P.v[2] : P.v[3]; };
    auto rptr = [&](int m) { return (m == 0) ? P.rg[0] : (m == 1) ? P.rg[1] : (m == 2) ? P.rg[2] : P.rg[3]; };

    // ---- active-chunk list packed as nibbles (block-uniform, stays scalar) ----
    unsigned long long clist = 0ull; int nc = 0;
    for (int m = 0; m < 4; ++m) {
        if (actm[m]) {
            #pragma unroll
            for (int s = 0; s < 4; ++s) { clist |= ((unsigned long long)(m * 4 + s)) << (4 * nc); ++nc; }
        }
    }

    // ---------------- chunk prefetch registers (4 token-groups per wave) ----------------
    float4 pkf[4], pvf[4];
    auto prefetch = [&](int cj) {
        const int mod = cj >> 2, j = cj & 3;
        const int g = rptr(mod)[rgbase + j] & 63;
        const int goff = (((g >> 4) & 3) << 10) + (((g >> 2) & 3) << 6) + ((g & 3) << 2);
        const float* ks = kptr(mod);
        const float* vs = vptr(mod);
        const int off0 = bh_base + lane * 4096 + goff;
        #pragma unroll
        for (int i = 0; i < 4; ++i) {
            const int pq = wave * 4 + i;
            const int off = off0 + (pq >> 2) * 256 + (pq & 3) * 16;
            pkf[i] = *(const float4*)(ks + off);
            pvf[i] = *(const float4*)(vs + off);
        }
    };

    auto stage = [&](int buf) {
        ushort* Kb = SMEM + buf * 9216;
        ushort* Vb = Kb + 4608;
        #pragma unroll
        for (int i = 0; i < 4; ++i) {
            const int pq = wave * 4 + i;
            unsigned k01 = pkbf(pkf[i].x, pkf[i].y);
            unsigned k23 = pkbf(pkf[i].z, pkf[i].w);
            ushort* kb = &Kb[(pq * 4) * LDK + lane];
            kb[0 * LDK] = (ushort)k01;
            kb[1 * LDK] = (ushort)(k01 >> 16);
            kb[2 * LDK] = (ushort)k23;
            kb[3 * LDK] = (ushort)(k23 >> 16);
            uint2 vv;
            vv.x = pkbf(pvf[i].x, pvf[i].y);
            vv.y = pkbf(pvf[i].z, pvf[i].w);
            *(uint2*)&Vb[lane * LDK + pq * 4] = vv;   // transposed, packed 8B
        }
    };

    prefetch((int)(clist & 15));   // chunk-0 loads overlap Q staging below

    // ------- Q staging: per-wave PRIVATE 64 rows of SMEM scratch, ONE drain -------
    v8s qfrag[4][2];
    {
        ushort* qbuf = SMEM + wave * 4608;
        const float* qsrc = (wave == 0) ? P.q[0] : (wave == 1) ? P.q[1] : (wave == 2) ? P.q[2] : P.q[3];
        #pragma unroll
        for (int rb = 0; rb < 4; ++rb) {          // rb = mt (p coordinate)
            #pragma unroll
            for (int i = 0; i < 4; ++i) {         // i = x coordinate; c = lane
                int off = bh_base + lane * 4096 + (H0 + rb) * 256 + (W0 + i) * 16 + D0;
                float4 cv = *(const float4*)(qsrc + off);
                unsigned q01 = pkbf(cv.x * SCALE_LOG2E, cv.y * SCALE_LOG2E);
                unsigned q23 = pkbf(cv.z * SCALE_LOG2E, cv.w * SCALE_LOG2E);
                ushort* qb = &qbuf[(rb * 16 + i * 4) * LDK + lane];
                qb[0 * LDK] = (ushort)q01;
                qb[1 * LDK] = (ushort)(q01 >> 16);
                qb[2 * LDK] = (ushort)q23;
                qb[3 * LDK] = (ushort)(q23 >> 16);
            }
        }
        __asm__ volatile("s_waitcnt lgkmcnt(0)" ::: "memory");   // wave-local write->read
        #pragma unroll
        for (int rb = 0; rb < 4; ++rb) {
            qfrag[rb][0] = *(const v8s*)&qbuf[(rb * 16 + l15) * LDK + quad * 8];
            qfrag[rb][1] = *(const v8s*)&qbuf[(rb * 16 + l15) * LDK + 32 + quad * 8];
        }
    }
    __syncthreads();               // scratch reads done before buf0 staging overwrites
    stage(0);
    if (nc > 1) prefetch((int)((clist >> 4) & 15));
    __syncthreads();               // buf0 visible to all waves

    v4f  oacc[4][4];              // [mt][t]: D[row=quad*4+r = q][col=l15 = d-within-t]
    float mrow[4], lrow[4];       // softmax state per mt; lrow is PER-LANE PARTIAL
                                  // (this lane's 16-key subset); quad-reduced in epilogue.
    #pragma unroll
    for (int mt = 0; mt < 4; ++mt) {
        mrow[mt] = -1e30f; lrow[mt] = 0.f;
        #pragma unroll
        for (int t = 0; t < 4; ++t) oacc[mt][t] = (v4f){0.f, 0.f, 0.f, 0.f};
    }

    int cur = 0;
    #pragma unroll 1
    for (int i = 0; i < nc; ++i) {             // all listed chunks are active
        // ---- overlap: stage NEXT chunk into other buffer; issue prefetch i+2 ----
        if (i + 1 < nc) {
            stage(cur ^ 1);
            if (i + 2 < nc) prefetch((int)((clist >> (4 * (i + 2))) & 15));
        }
        const ushort* Kb = SMEM + cur * 9216;
        const ushort* Vb = Kb + 4608;

        // ===== PHASE A: QK^T + softmax; P stays in registers =====
        float sv[4][4][4];      // [mt][nt][r]: key = nt*16+quad*4+r, q = l15
        #pragma unroll
        for (int nt = 0; nt < 4; ++nt) {
            v8s kf0 = *(const v8s*)&Kb[(nt * 16 + l15) * LDK + quad * 8];
            v8s kf1 = *(const v8s*)&Kb[(nt * 16 + l15) * LDK + 32 + quad * 8];
            __builtin_amdgcn_s_setprio(1);
            #pragma unroll
            for (int mt = 0; mt < 4; ++mt) {
                v4f acc = (v4f){0.f, 0.f, 0.f, 0.f};
                acc = __builtin_amdgcn_mfma_f32_16x16x32_bf16(kf0, qfrag[mt][0], acc, 0, 0, 0);
                acc = __builtin_amdgcn_mfma_f32_16x16x32_bf16(kf1, qfrag[mt][1], acc, 0, 0, 0);
                #pragma unroll
                for (int r = 0; r < 4; ++r) sv[mt][nt][r] = acc[r];
            }
            __builtin_amdgcn_s_setprio(0);
        }
        uint2 pa[4][4];    // [mt][nt]: bf16x4 A-frag: P[q=l15][key=nt*16+quad*4+r]
        #pragma unroll
        for (int mt = 0; mt < 4; ++mt) {
            // column (=q) max: v_max3-friendly tree, then across quads (xor 16, 32)
            float mx;
            {
                float a0 = fmaxf(fmaxf(sv[mt][0][0], sv[mt][0][1]), sv[mt][0][2]);
                float a1 = fmaxf(fmaxf(sv[mt][0][3], sv[mt][1][0]), sv[mt][1][1]);
                float a2 = fmaxf(fmaxf(sv[mt][1][2], sv[mt][1][3]), sv[mt][2][0]);
                float a3 = fmaxf(fmaxf(sv[mt][2][1], sv[mt][2][2]), sv[mt][2][3]);
                float a4 = fmaxf(fmaxf(sv[mt][3][0], sv[mt][3][1]), sv[mt][3][2]);
                mx = fmaxf(fmaxf(fmaxf(a0, a1), a2), fmaxf(fmaxf(a3, a4), sv[mt][3][3]));
            }
            mx = fmaxf(mx, __shfl_xor(mx, 16));
            mx = fmaxf(mx, __shfl_xor(mx, 32));

            // T13 defer-max: only rescale when some row's max grew by > THR (wave-uniform)
            if (!__all(mx - mrow[mt] <= RESCALE_THR)) {
                const float mnew  = fmaxf(mrow[mt], mx);
                const float alpha = fexp2(mrow[mt] - mnew);
                mrow[mt] = mnew;
                lrow[mt] *= alpha;             // partial-sum rescale (linear => exact)
                float alpha_row[4];
                #pragma unroll
                for (int r = 0; r < 4; ++r)
                    alpha_row[r] = __shfl(alpha, (quad << 4) | (quad * 4 + r));
                #pragma unroll
                for (int t = 0; t < 4; ++t)
                    #pragma unroll
                    for (int r = 0; r < 4; ++r) oacc[mt][t][r] *= alpha_row[r];
            }
            const float mcur = mrow[mt];

            // P = exp2(S - m), single v_exp_f32 each; accumulate PER-LANE partial l
            // (no cross-lane reduction here — deferred to epilogue).
            float rsum = 0.f;
            #pragma unroll
            for (int nt = 0; nt < 4; ++nt) {
                float p0 = fexp2(sv[mt][nt][0] - mcur);
                float p1 = fexp2(sv[mt][nt][1] - mcur);
                float p2 = fexp2(sv[mt][nt][2] - mcur);
                float p3 = fexp2(sv[mt][nt][3] - mcur);
                rsum += (p0 + p1) + (p2 + p3);
                pa[mt][nt].x = pkbf(p0, p1);
                pa[mt][nt].y = pkbf(p2, p3);
            }
            lrow[mt] += rsum;
        }

        // ===== PHASE B: PV via 16x16x16 MFMA; vf shared across all 4 mt =====
        __builtin_amdgcn_s_setprio(1);
        #pragma unroll
        for (int t = 0; t < 4; ++t) {
            #pragma unroll
            for (int nt = 0; nt < 4; ++nt) {
                v4s vf = *(const v4s*)&Vb[(t * 16 + l15) * LDK + nt * 16 + quad * 4];
                #pragma unroll
                for (int mt = 0; mt < 4; ++mt)
                    oacc[mt][t] = mfma16(__builtin_bit_cast(v4s, pa[mt][nt]), vf, oacc[mt][t]);
            }
        }
        __builtin_amdgcn_s_setprio(0);

        __syncthreads();     // staged chunk i+1 visible; buf[cur] reads complete
        cur ^= 1;
    }

    // ---- epilogue: quad-reduce deferred l, O /= l (quad-transposed), seq2grid stores ----
    const int obase = (wave * 2 + b) * 1048576 + h * 64 * 4096;
    #pragma unroll
    for (int mt = 0; mt < 4; ++mt) {
        float lq = lrow[mt];
        lq += __shfl_xor(lq, 16);
        lq += __shfl_xor(lq, 32);              // full l for q = l15, dup across quads
        const float invq = 1.0f / lq;
        float inv_row[4];
        #pragma unroll
        for (int r = 0; r < 4; ++r)
            inv_row[r] = __shfl(invq, (quad << 4) | (quad * 4 + r));
        #pragma unroll
        for (int t = 0; t < 4; ++t) {
            float4 ov;
            ov.x = oacc[mt][t][0] * inv_row[0];
            ov.y = oacc[mt][t][1] * inv_row[1];
            ov.z = oacc[mt][t][2] * inv_row[2];
            ov.w = oacc[mt][t][3] * inv_row[3];
            int off = obase + (t * 16 + l15) * 4096 + (H0 + mt) * 256 + (W0 + quad) * 16 + D0;
            *(float4*)(P.out + off) = ov;
        }
    }
}

extern "C" void kernel_launch(void* const* d_in, const int* in_sizes, int n_in,
                              void* d_out, int out_size, void* d_ws, size_t ws_size,
                              hipStream_t stream) {
    (void)in_sizes; (void)n_in; (void)out_size; (void)d_ws; (void)ws_size;
    MMRAParams P;
    P.mask = (const int*)d_in[0];
    for (int i = 0; i < 4; ++i) {
        P.q[i]  = (const float*)d_in[1 + i];
        P.k[i]  = (const float*)d_in[5 + i];
        P.v[i]  = (const float*)d_in[9 + i];
        P.rg[i] = (const int*)d_in[13 + i];
    }
    P.out = (float*)d_out;
    hipLaunchKernelGGL(mmra_attn, dim3(512), dim3(256), 0, stream, P);
}